// Round 4
// baseline (213.241 us; speedup 1.0000x reference)
//
#include <hip/hip_runtime.h>

// RaggedAttention on MI355X — bf16 MFMA pipeline, barrier-free GEMMs.
// XP bf16[32768][256]; WCAT bf16[768][256] ([f][c] = B^T input); Q,K bf16[bh][512][32]
// (Q pre-scaled by log2e/sqrt(32)); Vt bf16[bh][32][512]; Y bf16[32768][256].
// MFMA 16x16x32_bf16 mappings (HW-verified per guide):
//   A-frag: lane holds A[m=lane&15][k=(lane>>4)*8+j]
//   B-frag: lane holds B[k=(lane>>4)*8+j][n=lane&15]  (row-major [n][k] source)
//   C/D   : lane reg r holds D[row=(lane>>4)*4+r][col=lane&15]
// GEMMs: per-wave producer-consumer. B-panel (32n x 256k) lives in 64 VGPRs,
// loaded once. A staged into per-wave private 3-stage LDS slabs via
// global_load_lds(16B); ordering by the wave's OWN s_waitcnt vmcnt(4) only —
// no s_barrier / __syncthreads anywhere in the K-loop. LDS chunk swizzle
// c ^ ((row>>1)&3) keeps frag ds_read_b128 at 2-way banks (free, m136).

typedef __attribute__((ext_vector_type(8))) short short8;
typedef __attribute__((ext_vector_type(4))) float f32x4;

#define N_TOTAL 24576
#define B_ 64
#define T_ 512
#define DM 256
#define NH 8
#define HD 32

// log2(e)/sqrt(HD) — folded into Q at projection time
#define QSCALE 0.25503463f

__device__ __forceinline__ unsigned short f2bf(float f) {
  unsigned int u = __float_as_uint(f);
  u += 0x7fffu + ((u >> 16) & 1u);   // RNE
  return (unsigned short)(u >> 16);
}

__device__ __forceinline__ void gl_lds16(const void* g, void* l) {
  __builtin_amdgcn_global_load_lds(
      (const __attribute__((address_space(1))) unsigned int*)g,
      (__attribute__((address_space(3))) unsigned int*)l, 16, 0, 0);
}

// ---------------- kernel 0: gather + bf16 cast + weight packing ----------------
__global__ __launch_bounds__(256) void pack_kernel(
    const float* __restrict__ x, const float* __restrict__ Wq,
    const float* __restrict__ Wk, const float* __restrict__ Wv,
    const float* __restrict__ Wp, const float* __restrict__ bq,
    const float* __restrict__ bk, const float* __restrict__ bv,
    const int* __restrict__ idx,
    short* __restrict__ XP, short* __restrict__ WCAT, short* __restrict__ WPb,
    float* __restrict__ BCAT) {
  int gid = blockIdx.x * 256 + threadIdx.x;
  if (gid < 768)
    BCAT[gid] = (gid < 256) ? bq[gid] : (gid < 512 ? bk[gid - 256] : bv[gid - 512]);
  const float* src;
  short* dst;
  if (gid < 1048576) {
    int row = gid >> 5, seg = gid & 31;
    src = x + (size_t)idx[row] * DM + seg * 8;
    dst = XP + (size_t)gid * 8;
  } else if (gid < 1073152) {
    int u = gid - 1048576;
    int f = u >> 5, seg = u & 31;
    const float* W = (f < 256) ? Wq : ((f < 512) ? Wk : Wv);
    src = W + (size_t)(f & 255) * DM + seg * 8;
    dst = WCAT + (size_t)u * 8;
  } else {
    int u = gid - 1073152;
    src = Wp + (size_t)u * 8;
    dst = WPb + (size_t)u * 8;
  }
  const float4* s4 = (const float4*)src;
  float4 a = s4[0], b = s4[1];
  short8 o;
  o[0] = (short)f2bf(a.x); o[1] = (short)f2bf(a.y);
  o[2] = (short)f2bf(a.z); o[3] = (short)f2bf(a.w);
  o[4] = (short)f2bf(b.x); o[5] = (short)f2bf(b.y);
  o[6] = (short)f2bf(b.z); o[7] = (short)f2bf(b.w);
  *(short8*)dst = o;
}

// ---------------- kernel 1: QKV GEMM (M=32768,N=768,K=256), barrier-free ------
// Block 128m x 64n, wave = 64m x 32n (4 mt x 2 nt). B in regs; A per-wave slabs.
__global__ __launch_bounds__(256) void qkv_gemm(
    const short* __restrict__ XP, const short* __restrict__ WCAT,
    const float* __restrict__ BCAT,
    unsigned short* __restrict__ Qb, unsigned short* __restrict__ Kb,
    unsigned short* __restrict__ Vt) {
  __shared__ __align__(16) char smem[4 * 3 * 4096];   // [wave][stage][4KB]
  int tid = threadIdx.x;
  int lane = tid & 63, w = tid >> 6;
  int i = lane & 15, q = lane >> 4;
  int m0 = blockIdx.x * 128, n0 = blockIdx.y * 64;
  int wm = (w & 1) * 64, wn = (w >> 1) * 32;
  int csa = q ^ ((i >> 1) & 3);
  char* slab0 = smem + w * 12288;

  // B panel in registers: breg[nt][ks] = WCAT[n0+wn+nt*16+i][ks*32 + q*8 ..+8]
  short8 breg[2][8];
#pragma unroll
  for (int nt = 0; nt < 2; nt++)
#pragma unroll
    for (int ks = 0; ks < 8; ks++)
      breg[nt][ks] =
          *(const short8*)&WCAT[(size_t)(n0 + wn + nt * 16 + i) * DM + ks * 32 + q * 8];

  // per-wave A staging: stage s covers rows m0+wm+[0,64) x 32 k, swizzled chunks
  int srow = lane >> 2;                       // local row within 16-row group
  auto stage = [&](int k, int s) {
    char* sb = slab0 + s * 4096;
#pragma unroll
    for (int j = 0; j < 4; j++) {
      int lr = j * 16 + srow;
      int c = (lane & 3) ^ ((lr >> 1) & 3);
      gl_lds16(XP + (size_t)(m0 + wm + lr) * DM + k * 32 + c * 8,
               sb + j * 1024 + lane * 16);
    }
  };

  f32x4 zf = {0.f, 0.f, 0.f, 0.f};
  f32x4 acc[4][2];
#pragma unroll
  for (int mt = 0; mt < 4; mt++) { acc[mt][0] = zf; acc[mt][1] = zf; }

  stage(0, 0);
  stage(1, 1);
#pragma unroll
  for (int k = 0; k < 8; k++) {
    if (k == 7)
      asm volatile("s_waitcnt vmcnt(0)" ::: "memory");
    else
      asm volatile("s_waitcnt vmcnt(4)" ::: "memory");
    const short* Asb = (const short*)(slab0 + (k % 3) * 4096);
    short8 a[4];
#pragma unroll
    for (int mt = 0; mt < 4; mt++)
      a[mt] = *(const short8*)&Asb[(mt * 16 + i) * 32 + csa * 8];
    if (k < 6) stage(k + 2, (k + 2) % 3);
#pragma unroll
    for (int mt = 0; mt < 4; mt++) {
      acc[mt][0] = __builtin_amdgcn_mfma_f32_16x16x32_bf16(a[mt], breg[0][k], acc[mt][0], 0, 0, 0);
      acc[mt][1] = __builtin_amdgcn_mfma_f32_16x16x32_bf16(a[mt], breg[1][k], acc[mt][1], 0, 0, 0);
    }
  }

  // epilogue: bias + scatter into Q [bh][t][d] (pre-scaled), K [bh][t][d], Vt [bh][d][t]
#pragma unroll
  for (int nt = 0; nt < 2; nt++) {
    int f = n0 + wn + nt * 16 + i;
    float bias = BCAT[f];
    int which = f >> 8;          // 0=q 1=k 2=v (uniform per block)
    int fw = f & 255;
    int hh = fw >> 5, dd = fw & 31;
#pragma unroll
    for (int mt = 0; mt < 4; mt++) {
#pragma unroll
      for (int r = 0; r < 4; r++) {
        int token = m0 + wm + mt * 16 + q * 4 + r;
        int bb = token >> 9, tt = token & 511;
        int bh = bb * NH + hh;
        float val = acc[mt][nt][r] + bias;
        if (which == 0)
          Qb[((size_t)bh * T_ + tt) * HD + dd] = f2bf(val * QSCALE);
        else if (which == 1)
          Kb[((size_t)bh * T_ + tt) * HD + dd] = f2bf(val);
        else
          Vt[((size_t)bh * HD + dd) * T_ + tt] = f2bf(val);
      }
    }
  }
}

// ---------------- kernel 2: attention ----------------
// block = 4 waves; wave = 64 t-rows of one (b,h); s-step 32, K rows interleaved
// (lane i holds s=2i,2i+1 -> adjacent P entries -> b32 writes + v_perm pack).
// Mask applied pre-exp (cndmask to -1e9); denominator via ones-column MFMA on
// the SAME truncated P fragments (truncation consistent in num/denom).
__global__ __launch_bounds__(256) void attn_kernel(
    const short* __restrict__ Qb, const short* __restrict__ Kb,
    const short* __restrict__ Vt, const int* __restrict__ batch,
    unsigned short* __restrict__ Y) {
  __shared__ __align__(16) short pscr[4][64 * 40];  // per-wave P scratch [t][s], pad 40
  __shared__ int sbat[T_];
  int tid = threadIdx.x, w = tid >> 6, lane = tid & 63;
  int i = lane & 15, q = lane >> 4;
  int bx = blockIdx.x;
  // grid = half*512 + bh : both halves of a bh land on the same XCD (512%8==0)
  int half = bx >> 9, bh = bx & 511;
  int b = bh >> 3, h = bh & 7;
  int t0 = half * 256 + w * 64;

  *(int2*)&sbat[tid * 2] = *(const int2*)&batch[b * T_ + tid * 2];
  __syncthreads();

  const short* Kbase = Kb + (size_t)bh * T_ * HD;
  const short* Vbase = Vt + (size_t)bh * HD * T_;
  short* pw = &pscr[w][0];

  short8 qf[4];
  int btv[4][4];
#pragma unroll
  for (int mt = 0; mt < 4; mt++)
    qf[mt] = *(const short8*)&Qb[((size_t)bh * T_ + t0 + mt * 16 + i) * HD + q * 8];
#pragma unroll
  for (int mt = 0; mt < 4; mt++) {
    int4 t4 = *(int4*)&sbat[t0 + mt * 16 + q * 4];
    btv[mt][0] = t4.x; btv[mt][1] = t4.y; btv[mt][2] = t4.z; btv[mt][3] = t4.w;
  }

  // ones B-fragment: B[k][n] = (n==0) ? 1.0bf16 : 0
  unsigned short ob = (i == 0) ? (unsigned short)0x3F80 : (unsigned short)0;
  short8 ones = {(short)ob, (short)ob, (short)ob, (short)ob,
                 (short)ob, (short)ob, (short)ob, (short)ob};

  f32x4 zf = {0.f, 0.f, 0.f, 0.f};
  f32x4 o[4][2], lacc[4];
#pragma unroll
  for (int mt = 0; mt < 4; mt++) {
    o[mt][0] = zf; o[mt][1] = zf; lacc[mt] = zf;
  }

  for (int s0 = 0; s0 < T_; s0 += 32) {
    // interleaved K rows: tile0 col n <-> s0+2n, tile1 col n <-> s0+2n+1
    short8 k0f = *(const short8*)&Kbase[(s0 + 2 * i) * HD + q * 8];
    short8 k1f = *(const short8*)&Kbase[(s0 + 2 * i + 1) * HD + q * 8];
    short8 v0f = *(const short8*)&Vbase[(size_t)i * T_ + s0 + q * 8];
    short8 v1f = *(const short8*)&Vbase[(size_t)(16 + i) * T_ + s0 + q * 8];
    int bs0 = sbat[s0 + 2 * i];
    int bs1 = sbat[s0 + 2 * i + 1];
#pragma unroll
    for (int mt = 0; mt < 4; mt++) {
      f32x4 st0 = __builtin_amdgcn_mfma_f32_16x16x32_bf16(qf[mt], k0f, zf, 0, 0, 0);
      f32x4 st1 = __builtin_amdgcn_mfma_f32_16x16x32_bf16(qf[mt], k1f, zf, 0, 0, 0);
#pragma unroll
      for (int r = 0; r < 4; r++) {
        float m0v = (btv[mt][r] == bs0) ? -1e9f : st0[r];
        float m1v = (btv[mt][r] == bs1) ? -1e9f : st1[r];
        unsigned e0 = __float_as_uint(__builtin_amdgcn_exp2f(m0v));
        unsigned e1 = __float_as_uint(__builtin_amdgcn_exp2f(m1v));
        // pack hi16(e0) | hi16(e1)<<16 : one v_perm_b32
        unsigned pk = __builtin_amdgcn_perm(e1, e0, 0x07060302u);
        *(unsigned*)&pw[(mt * 16 + q * 4 + r) * 40 + 2 * i] = pk;
      }
    }
#pragma unroll
    for (int mt = 0; mt < 4; mt++) {
      short8 pa = *(short8*)&pw[(mt * 16 + i) * 40 + q * 8];
      o[mt][0] = __builtin_amdgcn_mfma_f32_16x16x32_bf16(pa, v0f, o[mt][0], 0, 0, 0);
      o[mt][1] = __builtin_amdgcn_mfma_f32_16x16x32_bf16(pa, v1f, o[mt][1], 0, 0, 0);
      lacc[mt] = __builtin_amdgcn_mfma_f32_16x16x32_bf16(pa, ones, lacc[mt], 0, 0, 0);
    }
  }

#pragma unroll
  for (int mt = 0; mt < 4; mt++) {
#pragma unroll
    for (int r = 0; r < 4; r++) {
      float lv = __shfl(lacc[mt][r], lane & 48, 64);  // col 0 of this row-quad
      float inv = __builtin_amdgcn_rcpf(lv);
      size_t yb = ((size_t)b * T_ + t0 + mt * 16 + q * 4 + r) * DM + h * HD;
      Y[yb + i] = f2bf(o[mt][0][r] * inv);
      Y[yb + 16 + i] = f2bf(o[mt][1][r] * inv);
    }
  }
}

// ---------------- kernel 3: output GEMM, gathered A rows, barrier-free --------
// out[i][f] = sum_c Y[inv[i]][c] * Wp[f][c] + bp[f]; M=24576,N=256,K=256.
__global__ __launch_bounds__(256) void out_gemm(
    const short* __restrict__ Y, const short* __restrict__ WPb,
    const float* __restrict__ bp, const int* __restrict__ inv,
    float* __restrict__ out) {
  __shared__ __align__(16) char smem[4 * 3 * 4096];
  int tid = threadIdx.x;
  int lane = tid & 63, w = tid >> 6;
  int i = lane & 15, q = lane >> 4;
  int m0 = blockIdx.x * 128, n0 = blockIdx.y * 64;
  int wm = (w & 1) * 64, wn = (w >> 1) * 32;
  int csa = q ^ ((i >> 1) & 3);
  char* slab0 = smem + w * 12288;

  short8 breg[2][8];
#pragma unroll
  for (int nt = 0; nt < 2; nt++)
#pragma unroll
    for (int ks = 0; ks < 8; ks++)
      breg[nt][ks] =
          *(const short8*)&WPb[(size_t)(n0 + wn + nt * 16 + i) * DM + ks * 32 + q * 8];

  int srow = lane >> 2;
  int ivj[4];
#pragma unroll
  for (int j = 0; j < 4; j++) ivj[j] = inv[m0 + wm + j * 16 + srow];

  auto stage = [&](int k, int s) {
    char* sb = slab0 + s * 4096;
#pragma unroll
    for (int j = 0; j < 4; j++) {
      int lr = j * 16 + srow;
      int c = (lane & 3) ^ ((lr >> 1) & 3);
      gl_lds16(Y + (size_t)ivj[j] * DM + k * 32 + c * 8, sb + j * 1024 + lane * 16);
    }
  };

  f32x4 zf = {0.f, 0.f, 0.f, 0.f};
  f32x4 acc[4][2];
#pragma unroll
  for (int mt = 0; mt < 4; mt++) { acc[mt][0] = zf; acc[mt][1] = zf; }

  stage(0, 0);
  stage(1, 1);
#pragma unroll
  for (int k = 0; k < 8; k++) {
    if (k == 7)
      asm volatile("s_waitcnt vmcnt(0)" ::: "memory");
    else
      asm volatile("s_waitcnt vmcnt(4)" ::: "memory");
    const short* Asb = (const short*)(slab0 + (k % 3) * 4096);
    short8 a[4];
#pragma unroll
    for (int mt = 0; mt < 4; mt++)
      a[mt] = *(const short8*)&Asb[(mt * 16 + i) * 32 + csa * 8];
    if (k < 6) stage(k + 2, (k + 2) % 3);
#pragma unroll
    for (int mt = 0; mt < 4; mt++) {
      acc[mt][0] = __builtin_amdgcn_mfma_f32_16x16x32_bf16(a[mt], breg[0][k], acc[mt][0], 0, 0, 0);
      acc[mt][1] = __builtin_amdgcn_mfma_f32_16x16x32_bf16(a[mt], breg[1][k], acc[mt][1], 0, 0, 0);
    }
  }

#pragma unroll
  for (int nt = 0; nt < 2; nt++) {
    int f = n0 + wn + nt * 16 + i;
    float bias = bp[f];
#pragma unroll
    for (int mt = 0; mt < 4; mt++) {
#pragma unroll
      for (int r = 0; r < 4; r++) {
        int row = m0 + wm + mt * 16 + q * 4 + r;
        out[(size_t)row * DM + f] = acc[mt][nt][r] + bias;
      }
    }
  }
}

// ---------------- launch ----------------
extern "C" void kernel_launch(void* const* d_in, const int* in_sizes, int n_in,
                              void* d_out, int out_size, void* d_ws, size_t ws_size,
                              hipStream_t stream) {
  const float* x = (const float*)d_in[0];
  const float* Wq = (const float*)d_in[1];
  const float* bq = (const float*)d_in[2];
  const float* Wk = (const float*)d_in[3];
  const float* bk = (const float*)d_in[4];
  const float* Wv = (const float*)d_in[5];
  const float* bv = (const float*)d_in[6];
  const float* Wp = (const float*)d_in[7];
  const float* bp = (const float*)d_in[8];
  const int* idx = (const int*)d_in[9];
  const int* batch = (const int*)d_in[10];
  const int* inv = (const int*)d_in[11];
  float* out = (float*)d_out;

  char* ws = (char*)d_ws;
  short* XP = (short*)(ws + 0);                         // 16,777,216 B
  short* WCAT = (short*)(ws + 16777216);                //    393,216 B
  short* WPb = (short*)(ws + 17170432);                 //    131,072 B
  float* BCAT = (float*)(ws + 17301504);                //      3,072 B
  unsigned short* Qb = (unsigned short*)(ws + 17304576);  // 16,777,216 B
  unsigned short* Kb = (unsigned short*)(ws + 34081792);  // 16,777,216 B
  unsigned short* Vt = (unsigned short*)(ws + 50859008);  // 16,777,216 B
  unsigned short* Yb = (unsigned short*)(ws + 67636224);  // 16,777,216 B
  // total ws use: 84,413,440 B

  pack_kernel<<<4224, 256, 0, stream>>>(x, Wq, Wk, Wv, Wp, bq, bk, bv, idx,
                                        XP, WCAT, WPb, BCAT);
  qkv_gemm<<<dim3(256, 12), 256, 0, stream>>>(XP, WCAT, BCAT, Qb, Kb, Vt);
  attn_kernel<<<1024, 256, 0, stream>>>((const short*)Qb, (const short*)Kb,
                                        (const short*)Vt, batch, Yb);
  out_gemm<<<dim3(192, 4), 256, 0, stream>>>((const short*)Yb, WPb, bp, inv, out);
}

// Round 5
// 199.895 us; speedup vs baseline: 1.0668x; 1.0668x over previous
//
#include <hip/hip_runtime.h>

// RaggedAttention on MI355X — bf16 MFMA pipeline.
// XP bf16[32768][256]; WCAT bf16[768][256] ([f][c] = B^T input); Q,K bf16[bh][512][32]
// (Q pre-scaled by log2e/sqrt(32)); Vt bf16[bh][32][512]; Y bf16[32768][256].
// MFMA 16x16x32_bf16 mappings (HW-verified per guide):
//   A-frag: lane holds A[m=lane&15][k=(lane>>4)*8+j]
//   B-frag: lane holds B[k=(lane>>4)*8+j][n=lane&15]  (row-major [n][k] source)
//   C/D   : lane reg r holds D[row=(lane>>4)*4+r][col=lane&15]
// GEMMs: B-panel register-resident (loaded once per block); only A staged to LDS
// via global_load_lds(16B), 3-slab pipeline, s_waitcnt vmcnt(2)+lgkmcnt(0)+s_barrier
// per iter (stage g+1 always in flight). qkv runs an m-loop of 2 tiles so each
// block has 16 pipelined K-iters (prologue amortized). XOR chunk swizzle
// c^((row>>1)&3): frag ds_read_b128 at 2-way banks = free (verified 0 conflicts r3).

typedef __attribute__((ext_vector_type(8))) short short8;
typedef __attribute__((ext_vector_type(4))) float f32x4;

#define N_TOTAL 24576
#define B_ 64
#define T_ 512
#define DM 256
#define NH 8
#define HD 32

// log2(e)/sqrt(HD) — folded into Q at projection time
#define QSCALE 0.25503463f

__device__ __forceinline__ unsigned short f2bf(float f) {
  unsigned int u = __float_as_uint(f);
  u += 0x7fffu + ((u >> 16) & 1u);   // RNE
  return (unsigned short)(u >> 16);
}

__device__ __forceinline__ void gl_lds16(const void* g, void* l) {
  __builtin_amdgcn_global_load_lds(
      (const __attribute__((address_space(1))) unsigned int*)g,
      (__attribute__((address_space(3))) unsigned int*)l, 16, 0, 0);
}

// ---------------- kernel 0: gather + bf16 cast + weight packing ----------------
__global__ __launch_bounds__(256) void pack_kernel(
    const float* __restrict__ x, const float* __restrict__ Wq,
    const float* __restrict__ Wk, const float* __restrict__ Wv,
    const float* __restrict__ Wp, const float* __restrict__ bq,
    const float* __restrict__ bk, const float* __restrict__ bv,
    const int* __restrict__ idx,
    short* __restrict__ XP, short* __restrict__ WCAT, short* __restrict__ WPb,
    float* __restrict__ BCAT) {
  int gid = blockIdx.x * 256 + threadIdx.x;
  if (gid < 768)
    BCAT[gid] = (gid < 256) ? bq[gid] : (gid < 512 ? bk[gid - 256] : bv[gid - 512]);
  const float* src;
  short* dst;
  if (gid < 1048576) {
    int row = gid >> 5, seg = gid & 31;
    src = x + (size_t)idx[row] * DM + seg * 8;
    dst = XP + (size_t)gid * 8;
  } else if (gid < 1073152) {
    int u = gid - 1048576;
    int f = u >> 5, seg = u & 31;
    const float* W = (f < 256) ? Wq : ((f < 512) ? Wk : Wv);
    src = W + (size_t)(f & 255) * DM + seg * 8;
    dst = WCAT + (size_t)u * 8;
  } else {
    int u = gid - 1073152;
    src = Wp + (size_t)u * 8;
    dst = WPb + (size_t)u * 8;
  }
  const float4* s4 = (const float4*)src;
  float4 a = s4[0], b = s4[1];
  short8 o;
  o[0] = (short)f2bf(a.x); o[1] = (short)f2bf(a.y);
  o[2] = (short)f2bf(a.z); o[3] = (short)f2bf(a.w);
  o[4] = (short)f2bf(b.x); o[5] = (short)f2bf(b.y);
  o[6] = (short)f2bf(b.z); o[7] = (short)f2bf(b.w);
  *(short8*)dst = o;
}

// ---------------- kernel 1: QKV GEMM (M=32768,N=768,K=256) --------------------
// Block: 256m x 128n as m-loop of 2 x (128m). 4 waves, wave = 64m x 64n.
// B panel per wave: 4nt x 8ks short8 = 128 VGPR, loaded once. A: 3x8KB LDS slabs.
__global__ __launch_bounds__(256, 2) void qkv_gemm(
    const short* __restrict__ XP, const short* __restrict__ WCAT,
    const float* __restrict__ BCAT,
    unsigned short* __restrict__ Qb, unsigned short* __restrict__ Kb,
    unsigned short* __restrict__ Vt) {
  __shared__ __align__(16) char smem[3 * 8192];
  int tid = threadIdx.x;
  int lane = tid & 63, w = tid >> 6;
  int i = lane & 15, q = lane >> 4;
  int mg = blockIdx.x;                 // 256-row m-group
  int n0 = blockIdx.y * 128;
  int wm = (w & 1) * 64, wn = (w >> 1) * 64;
  int csa = q ^ ((i >> 1) & 3);

  // B panel in registers (issued first; vmcnt(2) at first iter waits them too)
  short8 breg[4][8];
#pragma unroll
  for (int nt = 0; nt < 4; nt++)
#pragma unroll
    for (int ks = 0; ks < 8; ks++)
      breg[nt][ks] =
          *(const short8*)&WCAT[(size_t)(n0 + wn + nt * 16 + i) * DM + ks * 32 + q * 8];

  // stage global iter g (0..15): A rows mg*256 + (g>>3)*128, k-slice (g&7)*32
  auto stage = [&](int g) {
    char* sb = smem + (g % 3) * 8192;
    int rowbase = mg * 256 + ((g >> 3) << 7);
    int kk = (g & 7) * 32;
#pragma unroll
    for (int p = 0; p < 2; p++) {
      int U = p * 256 + tid;
      int row = U >> 2, c = U & 3;
      int cs = c ^ ((row >> 1) & 3);
      gl_lds16(XP + (size_t)(rowbase + row) * DM + kk + cs * 8, sb + U * 16);
    }
  };

  f32x4 zf = {0.f, 0.f, 0.f, 0.f};
  stage(0);
  stage(1);
#pragma unroll
  for (int mi = 0; mi < 2; mi++) {
    f32x4 acc[4][4];
#pragma unroll
    for (int mt = 0; mt < 4; mt++)
#pragma unroll
      for (int nt = 0; nt < 4; nt++) acc[mt][nt] = zf;

#pragma unroll
    for (int k = 0; k < 8; k++) {
      int g = mi * 8 + k;
      if (g == 15)
        asm volatile("s_waitcnt vmcnt(0) lgkmcnt(0)\ns_barrier" ::: "memory");
      else
        asm volatile("s_waitcnt vmcnt(2) lgkmcnt(0)\ns_barrier" ::: "memory");
      const short* Asb = (const short*)(smem + (g % 3) * 8192);
      short8 a[4];
#pragma unroll
      for (int mt = 0; mt < 4; mt++)
        a[mt] = *(const short8*)&Asb[(wm + mt * 16 + i) * 32 + csa * 8];
      if (g < 14) stage(g + 2);
#pragma unroll
      for (int mt = 0; mt < 4; mt++)
#pragma unroll
        for (int nt = 0; nt < 4; nt++)
          acc[mt][nt] = __builtin_amdgcn_mfma_f32_16x16x32_bf16(a[mt], breg[nt][k], acc[mt][nt], 0, 0, 0);
    }

    // epilogue for this m-tile: bias + scatter Q/K [bh][t][d], Vt [bh][d][t]
    int mbase = mg * 256 + mi * 128 + wm;
#pragma unroll
    for (int nt = 0; nt < 4; nt++) {
      int f = n0 + wn + nt * 16 + i;
      float bias = BCAT[f];
      int which = f >> 8;            // uniform per block (n0 128-aligned)
      int fw = f & 255;
      int hh = fw >> 5, dd = fw & 31;
#pragma unroll
      for (int mt = 0; mt < 4; mt++) {
#pragma unroll
        for (int r = 0; r < 4; r++) {
          int token = mbase + mt * 16 + q * 4 + r;
          int bb = token >> 9, tt = token & 511;
          int bh = bb * NH + hh;
          float val = acc[mt][nt][r] + bias;
          if (which == 0)
            Qb[((size_t)bh * T_ + tt) * HD + dd] = f2bf(val * QSCALE);
          else if (which == 1)
            Kb[((size_t)bh * T_ + tt) * HD + dd] = f2bf(val);
          else
            Vt[((size_t)bh * HD + dd) * T_ + tt] = f2bf(val);
        }
      }
    }
  }
}

// ---------------- kernel 2: attention ----------------
// block = 4 waves; wave = 64 t-rows of one (b,h); s-step 32, K rows interleaved
// (lane i holds s=2i,2i+1 -> adjacent P entries -> b32 writes + v_perm pack).
// Mask applied pre-exp (cndmask to -1e9); denominator via ones-column MFMA on
// the SAME truncated P fragments (truncation consistent in num/denom).
__global__ __launch_bounds__(256) void attn_kernel(
    const short* __restrict__ Qb, const short* __restrict__ Kb,
    const short* __restrict__ Vt, const int* __restrict__ batch,
    unsigned short* __restrict__ Y) {
  __shared__ __align__(16) short pscr[4][64 * 40];  // per-wave P scratch [t][s], pad 40
  __shared__ int sbat[T_];
  int tid = threadIdx.x, w = tid >> 6, lane = tid & 63;
  int i = lane & 15, q = lane >> 4;
  int bx = blockIdx.x;
  // grid = half*512 + bh : both halves of a bh land on the same XCD (512%8==0)
  int half = bx >> 9, bh = bx & 511;
  int b = bh >> 3, h = bh & 7;
  int t0 = half * 256 + w * 64;

  *(int2*)&sbat[tid * 2] = *(const int2*)&batch[b * T_ + tid * 2];
  __syncthreads();

  const short* Kbase = Kb + (size_t)bh * T_ * HD;
  const short* Vbase = Vt + (size_t)bh * HD * T_;
  short* pw = &pscr[w][0];

  short8 qf[4];
  int btv[4][4];
#pragma unroll
  for (int mt = 0; mt < 4; mt++)
    qf[mt] = *(const short8*)&Qb[((size_t)bh * T_ + t0 + mt * 16 + i) * HD + q * 8];
#pragma unroll
  for (int mt = 0; mt < 4; mt++) {
    int4 t4 = *(int4*)&sbat[t0 + mt * 16 + q * 4];
    btv[mt][0] = t4.x; btv[mt][1] = t4.y; btv[mt][2] = t4.z; btv[mt][3] = t4.w;
  }

  // ones B-fragment: B[k][n] = (n==0) ? 1.0bf16 : 0
  unsigned short ob = (i == 0) ? (unsigned short)0x3F80 : (unsigned short)0;
  short8 ones = {(short)ob, (short)ob, (short)ob, (short)ob,
                 (short)ob, (short)ob, (short)ob, (short)ob};

  f32x4 zf = {0.f, 0.f, 0.f, 0.f};
  f32x4 o[4][2], lacc[4];
#pragma unroll
  for (int mt = 0; mt < 4; mt++) {
    o[mt][0] = zf; o[mt][1] = zf; lacc[mt] = zf;
  }

  for (int s0 = 0; s0 < T_; s0 += 32) {
    // interleaved K rows: tile0 col n <-> s0+2n, tile1 col n <-> s0+2n+1
    short8 k0f = *(const short8*)&Kbase[(s0 + 2 * i) * HD + q * 8];
    short8 k1f = *(const short8*)&Kbase[(s0 + 2 * i + 1) * HD + q * 8];
    short8 v0f = *(const short8*)&Vbase[(size_t)i * T_ + s0 + q * 8];
    short8 v1f = *(const short8*)&Vbase[(size_t)(16 + i) * T_ + s0 + q * 8];
    int bs0 = sbat[s0 + 2 * i];
    int bs1 = sbat[s0 + 2 * i + 1];
#pragma unroll
    for (int mt = 0; mt < 4; mt++) {
      f32x4 st0 = __builtin_amdgcn_mfma_f32_16x16x32_bf16(qf[mt], k0f, zf, 0, 0, 0);
      f32x4 st1 = __builtin_amdgcn_mfma_f32_16x16x32_bf16(qf[mt], k1f, zf, 0, 0, 0);
#pragma unroll
      for (int r = 0; r < 4; r++) {
        float m0v = (btv[mt][r] == bs0) ? -1e9f : st0[r];
        float m1v = (btv[mt][r] == bs1) ? -1e9f : st1[r];
        unsigned e0 = __float_as_uint(__builtin_amdgcn_exp2f(m0v));
        unsigned e1 = __float_as_uint(__builtin_amdgcn_exp2f(m1v));
        // pack hi16(e0) | hi16(e1)<<16 : one v_perm_b32
        unsigned pk = __builtin_amdgcn_perm(e1, e0, 0x07060302u);
        *(unsigned*)&pw[(mt * 16 + q * 4 + r) * 40 + 2 * i] = pk;
      }
    }
#pragma unroll
    for (int mt = 0; mt < 4; mt++) {
      short8 pa = *(short8*)&pw[(mt * 16 + i) * 40 + q * 8];
      o[mt][0] = __builtin_amdgcn_mfma_f32_16x16x32_bf16(pa, v0f, o[mt][0], 0, 0, 0);
      o[mt][1] = __builtin_amdgcn_mfma_f32_16x16x32_bf16(pa, v1f, o[mt][1], 0, 0, 0);
      lacc[mt] = __builtin_amdgcn_mfma_f32_16x16x32_bf16(pa, ones, lacc[mt], 0, 0, 0);
    }
  }

#pragma unroll
  for (int mt = 0; mt < 4; mt++) {
#pragma unroll
    for (int r = 0; r < 4; r++) {
      float lv = __shfl(lacc[mt][r], lane & 48, 64);  // col 0 of this row-quad
      float inv = __builtin_amdgcn_rcpf(lv);
      size_t yb = ((size_t)b * T_ + t0 + mt * 16 + q * 4 + r) * DM + h * HD;
      Y[yb + i] = f2bf(o[mt][0][r] * inv);
      Y[yb + 16 + i] = f2bf(o[mt][1][r] * inv);
    }
  }
}

// ---------------- kernel 3: output GEMM, gathered A rows ----------------------
// out[i][f] = sum_c Y[inv[i]][c] * Wp[f][c] + bp[f]; M=24576,N=256,K=256.
// Block 128m x 64n, wave 64m x 32n; B in regs (64 VGPR); A via DMA gather.
__global__ __launch_bounds__(256, 3) void out_gemm(
    const short* __restrict__ Y, const short* __restrict__ WPb,
    const float* __restrict__ bp, const int* __restrict__ inv,
    float* __restrict__ out) {
  __shared__ __align__(16) char smem[3 * 8192];
  int tid = threadIdx.x;
  int lane = tid & 63, w = tid >> 6;
  int i = lane & 15, q = lane >> 4;
  int m0 = blockIdx.x * 128, n0 = blockIdx.y * 64;
  int wm = (w & 1) * 64, wn = (w >> 1) * 32;
  int csa = q ^ ((i >> 1) & 3);

  short8 breg[2][8];
#pragma unroll
  for (int nt = 0; nt < 2; nt++)
#pragma unroll
    for (int ks = 0; ks < 8; ks++)
      breg[nt][ks] =
          *(const short8*)&WPb[(size_t)(n0 + wn + nt * 16 + i) * DM + ks * 32 + q * 8];

  int iv0 = inv[m0 + (tid >> 2)];
  int iv1 = inv[m0 + 64 + (tid >> 2)];

  auto stage = [&](int g) {
    char* sb = smem + (g % 3) * 8192;
    int kk = g * 32;
#pragma unroll
    for (int p = 0; p < 2; p++) {
      int U = p * 256 + tid;
      int row = U >> 2, c = U & 3;
      int cs = c ^ ((row >> 1) & 3);
      int iv = p ? iv1 : iv0;
      gl_lds16(Y + (size_t)iv * DM + kk + cs * 8, sb + U * 16);
    }
  };

  f32x4 zf = {0.f, 0.f, 0.f, 0.f};
  f32x4 acc[4][2];
#pragma unroll
  for (int mt = 0; mt < 4; mt++) { acc[mt][0] = zf; acc[mt][1] = zf; }

  stage(0);
  stage(1);
#pragma unroll
  for (int g = 0; g < 8; g++) {
    if (g == 7)
      asm volatile("s_waitcnt vmcnt(0) lgkmcnt(0)\ns_barrier" ::: "memory");
    else
      asm volatile("s_waitcnt vmcnt(2) lgkmcnt(0)\ns_barrier" ::: "memory");
    const short* Asb = (const short*)(smem + (g % 3) * 8192);
    short8 a[4];
#pragma unroll
    for (int mt = 0; mt < 4; mt++)
      a[mt] = *(const short8*)&Asb[(wm + mt * 16 + i) * 32 + csa * 8];
    if (g < 6) stage(g + 2);
#pragma unroll
    for (int mt = 0; mt < 4; mt++) {
      acc[mt][0] = __builtin_amdgcn_mfma_f32_16x16x32_bf16(a[mt], breg[0][g], acc[mt][0], 0, 0, 0);
      acc[mt][1] = __builtin_amdgcn_mfma_f32_16x16x32_bf16(a[mt], breg[1][g], acc[mt][1], 0, 0, 0);
    }
  }

#pragma unroll
  for (int nt = 0; nt < 2; nt++) {
    int f = n0 + wn + nt * 16 + i;
    float bias = bp[f];
#pragma unroll
    for (int mt = 0; mt < 4; mt++) {
#pragma unroll
      for (int r = 0; r < 4; r++) {
        int row = m0 + wm + mt * 16 + q * 4 + r;
        out[(size_t)row * DM + f] = acc[mt][nt][r] + bias;
      }
    }
  }
}

// ---------------- launch ----------------
extern "C" void kernel_launch(void* const* d_in, const int* in_sizes, int n_in,
                              void* d_out, int out_size, void* d_ws, size_t ws_size,
                              hipStream_t stream) {
  const float* x = (const float*)d_in[0];
  const float* Wq = (const float*)d_in[1];
  const float* bq = (const float*)d_in[2];
  const float* Wk = (const float*)d_in[3];
  const float* bk = (const float*)d_in[4];
  const float* Wv = (const float*)d_in[5];
  const float* bv = (const float*)d_in[6];
  const float* Wp = (const float*)d_in[7];
  const float* bp = (const float*)d_in[8];
  const int* idx = (const int*)d_in[9];
  const int* batch = (const int*)d_in[10];
  const int* inv = (const int*)d_in[11];
  float* out = (float*)d_out;

  char* ws = (char*)d_ws;
  short* XP = (short*)(ws + 0);                         // 16,777,216 B
  short* WCAT = (short*)(ws + 16777216);                //    393,216 B
  short* WPb = (short*)(ws + 17170432);                 //    131,072 B
  float* BCAT = (float*)(ws + 17301504);                //      3,072 B
  unsigned short* Qb = (unsigned short*)(ws + 17304576);  // 16,777,216 B
  unsigned short* Kb = (unsigned short*)(ws + 34081792);  // 16,777,216 B
  unsigned short* Vt = (unsigned short*)(ws + 50859008);  // 16,777,216 B
  unsigned short* Yb = (unsigned short*)(ws + 67636224);  // 16,777,216 B
  // total ws use: 84,413,440 B

  pack_kernel<<<4224, 256, 0, stream>>>(x, Wq, Wk, Wv, Wp, bq, bk, bv, idx,
                                        XP, WCAT, WPb, BCAT);
  qkv_gemm<<<dim3(128, 6), 256, 0, stream>>>(XP, WCAT, BCAT, Qb, Kb, Vt);
  attn_kernel<<<1024, 256, 0, stream>>>((const short*)Qb, (const short*)Kb,
                                        (const short*)Vt, batch, Yb);
  out_gemm<<<dim3(192, 4), 256, 0, stream>>>((const short*)Yb, WPb, bp, inv, out);
}

// Round 6
// 180.085 us; speedup vs baseline: 1.1841x; 1.1100x over previous
//
#include <hip/hip_runtime.h>

// RaggedAttention on MI355X — bf16 MFMA pipeline.
// XP bf16[32768][256]; WCAT bf16[768][256] ([f][c] = B^T input);
// QKVp bf16[32768][768]  (unified QKV output, GEMM-natural layout;
//   f<256: Q pre-scaled by log2e/sqrt(32); [256,512): K; [512,768): V)
// Y bf16[32768][256].
// MFMA 16x16x32_bf16 mappings (HW-verified per guide):
//   A-frag: lane holds A[m=lane&15][k=(lane>>4)*8+j]
//   B-frag: lane holds B[k=(lane>>4)*8+j][n=lane&15]  (row-major [n][k] source)
//   C/D   : lane reg r holds D[row=(lane>>4)*4+r][col=lane&15]
// Key lesson r2-r5: qkv dur ~= bytes/(1-1.7TB/s) regardless of K-loop -> the
// epilogue Vt scatter (64 lines per 64-lane store) was the bottleneck, not the
// K-loop. QKVp natural layout makes every store line-friendly; attn does the
// V transpose once per block in LDS instead.

typedef __attribute__((ext_vector_type(8))) short short8;
typedef __attribute__((ext_vector_type(4))) float f32x4;

#define N_TOTAL 24576
#define B_ 64
#define T_ 512
#define DM 256
#define NH 8
#define HD 32
#define F3 768

// log2(e)/sqrt(HD) — folded into Q at projection time
#define QSCALE 0.25503463f
#define VSP 514   // LDS V-tile row stride (shorts): write banks (8seg+j+s/2)%32 all distinct

__device__ __forceinline__ unsigned short f2bf(float f) {
  unsigned int u = __float_as_uint(f);
  u += 0x7fffu + ((u >> 16) & 1u);   // RNE
  return (unsigned short)(u >> 16);
}

__device__ __forceinline__ void gl_lds16(const void* g, void* l) {
  __builtin_amdgcn_global_load_lds(
      (const __attribute__((address_space(1))) unsigned int*)g,
      (__attribute__((address_space(3))) unsigned int*)l, 16, 0, 0);
}

// ---------------- kernel 0: gather + bf16 cast + weight packing ----------------
__global__ __launch_bounds__(256) void pack_kernel(
    const float* __restrict__ x, const float* __restrict__ Wq,
    const float* __restrict__ Wk, const float* __restrict__ Wv,
    const float* __restrict__ Wp, const float* __restrict__ bq,
    const float* __restrict__ bk, const float* __restrict__ bv,
    const int* __restrict__ idx,
    short* __restrict__ XP, short* __restrict__ WCAT, short* __restrict__ WPb,
    float* __restrict__ BCAT) {
  int gid = blockIdx.x * 256 + threadIdx.x;
  if (gid < 768)
    BCAT[gid] = (gid < 256) ? bq[gid] : (gid < 512 ? bk[gid - 256] : bv[gid - 512]);
  const float* src;
  short* dst;
  if (gid < 1048576) {
    int row = gid >> 5, seg = gid & 31;
    src = x + (size_t)idx[row] * DM + seg * 8;
    dst = XP + (size_t)gid * 8;
  } else if (gid < 1073152) {
    int u = gid - 1048576;
    int f = u >> 5, seg = u & 31;
    const float* W = (f < 256) ? Wq : ((f < 512) ? Wk : Wv);
    src = W + (size_t)(f & 255) * DM + seg * 8;
    dst = WCAT + (size_t)u * 8;
  } else {
    int u = gid - 1073152;
    src = Wp + (size_t)u * 8;
    dst = WPb + (size_t)u * 8;
  }
  const float4* s4 = (const float4*)src;
  float4 a = s4[0], b = s4[1];
  short8 o;
  o[0] = (short)f2bf(a.x); o[1] = (short)f2bf(a.y);
  o[2] = (short)f2bf(a.z); o[3] = (short)f2bf(a.w);
  o[4] = (short)f2bf(b.x); o[5] = (short)f2bf(b.y);
  o[6] = (short)f2bf(b.z); o[7] = (short)f2bf(b.w);
  *(short8*)dst = o;
}

// ---------------- kernel 1: QKV GEMM (M=32768,N=768,K=256) --------------------
// 128x128 tile, 4 waves (64x64). A+B staged via DMA, 3 slabs, vmcnt(4) pipeline
// (r3-proven, 0 bank conflicts). Epilogue: line-friendly unified QKVp store.
__global__ __launch_bounds__(256) void qkv_gemm(
    const short* __restrict__ XP, const short* __restrict__ WCAT,
    const float* __restrict__ BCAT, unsigned short* __restrict__ QKVp) {
  __shared__ __align__(16) char smem[3 * 16384];
  int tid = threadIdx.x;
  int lane = tid & 63, w = tid >> 6;
  int i = lane & 15, q = lane >> 4;
  int m0 = blockIdx.x * 128, n0 = blockIdx.y * 128;
  int wm = (w & 1) * 64, wn = (w >> 1) * 64;
  int csa = q ^ ((i >> 1) & 3);

  f32x4 zf = {0.f, 0.f, 0.f, 0.f};
  f32x4 acc[4][4];
#pragma unroll
  for (int mt = 0; mt < 4; mt++)
#pragma unroll
    for (int nt = 0; nt < 4; nt++) acc[mt][nt] = zf;

  auto stage = [&](int k, int s) {
#pragma unroll
    for (int p = 0; p < 2; p++) {
      int U = p * 256 + tid;
      int row = U >> 2, c = U & 3;
      int cs = c ^ ((row >> 1) & 3);
      gl_lds16(XP + (size_t)(m0 + row) * DM + k * 32 + cs * 8,
               smem + s * 16384 + U * 16);
      gl_lds16(WCAT + (size_t)(n0 + row) * DM + k * 32 + cs * 8,
               smem + s * 16384 + 8192 + U * 16);
    }
  };

  stage(0, 0);
  stage(1, 1);
#pragma unroll
  for (int k = 0; k < 8; k++) {
    if (k == 7)
      asm volatile("s_waitcnt vmcnt(0) lgkmcnt(0)\ns_barrier" ::: "memory");
    else
      asm volatile("s_waitcnt vmcnt(4) lgkmcnt(0)\ns_barrier" ::: "memory");
    const short* Asb = (const short*)(smem + (k % 3) * 16384);
    const short* Bsb = Asb + 4096;
    short8 a[4], bfr[4];
#pragma unroll
    for (int mt = 0; mt < 4; mt++)
      a[mt] = *(const short8*)&Asb[(wm + mt * 16 + i) * 32 + csa * 8];
#pragma unroll
    for (int nt = 0; nt < 4; nt++)
      bfr[nt] = *(const short8*)&Bsb[(wn + nt * 16 + i) * 32 + csa * 8];
    if (k < 6) stage(k + 2, (k + 2) % 3);
#pragma unroll
    for (int mt = 0; mt < 4; mt++)
#pragma unroll
      for (int nt = 0; nt < 4; nt++)
        acc[mt][nt] = __builtin_amdgcn_mfma_f32_16x16x32_bf16(a[mt], bfr[nt], acc[mt][nt], 0, 0, 0);
  }

  // epilogue: bias (+QSCALE for Q-part) and store to unified QKVp[token][f].
  // Per inst: 4 tokens x 16 consecutive cols (32B); nt pairs in the same wave
  // complete each 64B line.
  float scale = (n0 < 256) ? QSCALE : 1.0f;
#pragma unroll
  for (int nt = 0; nt < 4; nt++) {
    int f = n0 + wn + nt * 16 + i;
    float bias = BCAT[f];
#pragma unroll
    for (int mt = 0; mt < 4; mt++) {
#pragma unroll
      for (int r = 0; r < 4; r++) {
        int token = m0 + wm + mt * 16 + q * 4 + r;
        QKVp[(size_t)token * F3 + f] = f2bf((acc[mt][nt][r] + bias) * scale);
      }
    }
  }
}

// ---------------- kernel 2: attention ----------------
// block = 4 waves; wave = 64 t-rows of one (b,h); s-step 32.
// V transposed into LDS once per block (Vl[d][s], stride VSP, conflict-free
// writes). K rows interleaved (lane i <-> s=2i,2i+1) for adjacent P entries.
// Mask pre-exp; denominator via ones-column MFMA on the same truncated P.
__global__ __launch_bounds__(256) void attn_kernel(
    const unsigned short* __restrict__ QKVp, const int* __restrict__ batch,
    unsigned short* __restrict__ Y) {
  __shared__ __align__(16) short Vl[HD * VSP];      // 32,896 B
  __shared__ __align__(16) short pscr[4][64 * 40];  // 20,480 B
  __shared__ int sbat[T_];                          //  2,048 B
  int tid = threadIdx.x, w = tid >> 6, lane = tid & 63;
  int i = lane & 15, q = lane >> 4;
  int bx = blockIdx.x;
  // grid = half*512 + bh : both halves of a bh land on the same XCD (512%8==0)
  int half = bx >> 9, bh = bx & 511;
  int b = bh >> 3, h = bh & 7;
  int t0 = half * 256 + w * 64;
  const unsigned short* Tok = QKVp + (size_t)b * T_ * F3;  // this batch's rows

  *(int2*)&sbat[tid * 2] = *(const int2*)&batch[b * T_ + tid * 2];

  // V transpose: global [t][d] (64B head-aligned lines) -> LDS Vl[d][s]
  {
    int seg = tid & 3, sb = tid >> 2;   // seg: 8-d chunk; sb: s base
#pragma unroll
    for (int l = 0; l < 8; l++) {
      int s = sb + l * 64;
      short8 v = *(const short8*)&Tok[(size_t)s * F3 + 512 + h * HD + seg * 8];
#pragma unroll
      for (int j = 0; j < 8; j++) Vl[(seg * 8 + j) * VSP + s] = v[j];
    }
  }
  __syncthreads();

  short* pw = &pscr[w][0];

  short8 qf[4];
  int btv[4][4];
#pragma unroll
  for (int mt = 0; mt < 4; mt++)
    qf[mt] = *(const short8*)&Tok[(size_t)(t0 + mt * 16 + i) * F3 + h * HD + q * 8];
#pragma unroll
  for (int mt = 0; mt < 4; mt++) {
    int4 t4 = *(int4*)&sbat[t0 + mt * 16 + q * 4];
    btv[mt][0] = t4.x; btv[mt][1] = t4.y; btv[mt][2] = t4.z; btv[mt][3] = t4.w;
  }

  // ones B-fragment: B[k][n] = (n==0) ? 1.0bf16 : 0
  unsigned short ob = (i == 0) ? (unsigned short)0x3F80 : (unsigned short)0;
  short8 ones = {(short)ob, (short)ob, (short)ob, (short)ob,
                 (short)ob, (short)ob, (short)ob, (short)ob};

  f32x4 zf = {0.f, 0.f, 0.f, 0.f};
  f32x4 o[4][2], lacc[4];
#pragma unroll
  for (int mt = 0; mt < 4; mt++) {
    o[mt][0] = zf; o[mt][1] = zf; lacc[mt] = zf;
  }

  const unsigned short* Kcol = Tok + 256 + h * HD + q * 8;
  // software-prefetched K loads (interleaved rows: tile0 col n <-> s0+2n)
  short8 k0f = *(const short8*)&Kcol[(size_t)(2 * i) * F3];
  short8 k1f = *(const short8*)&Kcol[(size_t)(2 * i + 1) * F3];
  int bs0 = sbat[2 * i], bs1 = sbat[2 * i + 1];

  for (int s0 = 0; s0 < T_; s0 += 32) {
    short8 ck0 = k0f, ck1 = k1f;
    int cb0 = bs0, cb1 = bs1;
    if (s0 + 32 < T_) {
      k0f = *(const short8*)&Kcol[(size_t)(s0 + 32 + 2 * i) * F3];
      k1f = *(const short8*)&Kcol[(size_t)(s0 + 32 + 2 * i + 1) * F3];
      bs0 = sbat[s0 + 32 + 2 * i];
      bs1 = sbat[s0 + 32 + 2 * i + 1];
    }
    short8 v0f = *(const short8*)&Vl[i * VSP + s0 + q * 8];
    short8 v1f = *(const short8*)&Vl[(16 + i) * VSP + s0 + q * 8];
#pragma unroll
    for (int mt = 0; mt < 4; mt++) {
      f32x4 st0 = __builtin_amdgcn_mfma_f32_16x16x32_bf16(qf[mt], ck0, zf, 0, 0, 0);
      f32x4 st1 = __builtin_amdgcn_mfma_f32_16x16x32_bf16(qf[mt], ck1, zf, 0, 0, 0);
#pragma unroll
      for (int r = 0; r < 4; r++) {
        float m0v = (btv[mt][r] == cb0) ? -1e9f : st0[r];
        float m1v = (btv[mt][r] == cb1) ? -1e9f : st1[r];
        unsigned e0 = __float_as_uint(__builtin_amdgcn_exp2f(m0v));
        unsigned e1 = __float_as_uint(__builtin_amdgcn_exp2f(m1v));
        unsigned pk = __builtin_amdgcn_perm(e1, e0, 0x07060302u);
        *(unsigned*)&pw[(mt * 16 + q * 4 + r) * 40 + 2 * i] = pk;
      }
    }
#pragma unroll
    for (int mt = 0; mt < 4; mt++) {
      short8 pa = *(short8*)&pw[(mt * 16 + i) * 40 + q * 8];
      o[mt][0] = __builtin_amdgcn_mfma_f32_16x16x32_bf16(pa, v0f, o[mt][0], 0, 0, 0);
      o[mt][1] = __builtin_amdgcn_mfma_f32_16x16x32_bf16(pa, v1f, o[mt][1], 0, 0, 0);
      lacc[mt] = __builtin_amdgcn_mfma_f32_16x16x32_bf16(pa, ones, lacc[mt], 0, 0, 0);
    }
  }

#pragma unroll
  for (int mt = 0; mt < 4; mt++) {
#pragma unroll
    for (int r = 0; r < 4; r++) {
      float lv = __shfl(lacc[mt][r], lane & 48, 64);  // col 0 of this row-quad
      float inv = __builtin_amdgcn_rcpf(lv);
      size_t yb = ((size_t)b * T_ + t0 + mt * 16 + q * 4 + r) * DM + h * HD;
      Y[yb + i] = f2bf(o[mt][0][r] * inv);
      Y[yb + 16 + i] = f2bf(o[mt][1][r] * inv);
    }
  }
}

// ---------------- kernel 3: output GEMM, gathered A rows ----------------------
// out[i][f] = sum_c Y[inv[i]][c] * Wp[f][c] + bp[f]; M=24576,N=256,K=256.
// r3-proven structure: A (gathered) + B staged via DMA, vmcnt(4) pipeline.
__global__ __launch_bounds__(256) void out_gemm(
    const short* __restrict__ Y, const short* __restrict__ WPb,
    const float* __restrict__ bp, const int* __restrict__ inv,
    float* __restrict__ out) {
  __shared__ __align__(16) char smem[3 * 16384];
  int tid = threadIdx.x;
  int lane = tid & 63, w = tid >> 6;
  int i = lane & 15, q = lane >> 4;
  int m0 = blockIdx.x * 128, n0 = blockIdx.y * 128;
  int wm = (w & 1) * 64, wn = (w >> 1) * 64;
  int csa = q ^ ((i >> 1) & 3);

  int iv0 = inv[m0 + (tid >> 2)];
  int iv1 = inv[m0 + 64 + (tid >> 2)];

  f32x4 zf = {0.f, 0.f, 0.f, 0.f};
  f32x4 acc[4][4];
#pragma unroll
  for (int mt = 0; mt < 4; mt++)
#pragma unroll
    for (int nt = 0; nt < 4; nt++) acc[mt][nt] = zf;

  auto stage = [&](int k, int s) {
#pragma unroll
    for (int p = 0; p < 2; p++) {
      int U = p * 256 + tid;
      int row = U >> 2, c = U & 3;
      int cs = c ^ ((row >> 1) & 3);
      int iv = p ? iv1 : iv0;
      gl_lds16(Y + (size_t)iv * DM + k * 32 + cs * 8, smem + s * 16384 + U * 16);
      gl_lds16(WPb + (size_t)(n0 + row) * DM + k * 32 + cs * 8,
               smem + s * 16384 + 8192 + U * 16);
    }
  };

  stage(0, 0);
  stage(1, 1);
#pragma unroll
  for (int k = 0; k < 8; k++) {
    if (k == 7)
      asm volatile("s_waitcnt vmcnt(0) lgkmcnt(0)\ns_barrier" ::: "memory");
    else
      asm volatile("s_waitcnt vmcnt(4) lgkmcnt(0)\ns_barrier" ::: "memory");
    const short* Asb = (const short*)(smem + (k % 3) * 16384);
    const short* Bsb = Asb + 4096;
    short8 a[4], bfr[4];
#pragma unroll
    for (int mt = 0; mt < 4; mt++)
      a[mt] = *(const short8*)&Asb[(wm + mt * 16 + i) * 32 + csa * 8];
#pragma unroll
    for (int nt = 0; nt < 4; nt++)
      bfr[nt] = *(const short8*)&Bsb[(wn + nt * 16 + i) * 32 + csa * 8];
    if (k < 6) stage(k + 2, (k + 2) % 3);
#pragma unroll
    for (int mt = 0; mt < 4; mt++)
#pragma unroll
      for (int nt = 0; nt < 4; nt++)
        acc[mt][nt] = __builtin_amdgcn_mfma_f32_16x16x32_bf16(a[mt], bfr[nt], acc[mt][nt], 0, 0, 0);
  }

#pragma unroll
  for (int nt = 0; nt < 4; nt++) {
    int f = n0 + wn + nt * 16 + i;
    float bias = bp[f];
#pragma unroll
    for (int mt = 0; mt < 4; mt++) {
#pragma unroll
      for (int r = 0; r < 4; r++) {
        int row = m0 + wm + mt * 16 + q * 4 + r;
        out[(size_t)row * DM + f] = acc[mt][nt][r] + bias;
      }
    }
  }
}

// ---------------- launch ----------------
extern "C" void kernel_launch(void* const* d_in, const int* in_sizes, int n_in,
                              void* d_out, int out_size, void* d_ws, size_t ws_size,
                              hipStream_t stream) {
  const float* x = (const float*)d_in[0];
  const float* Wq = (const float*)d_in[1];
  const float* bq = (const float*)d_in[2];
  const float* Wk = (const float*)d_in[3];
  const float* bk = (const float*)d_in[4];
  const float* Wv = (const float*)d_in[5];
  const float* bv = (const float*)d_in[6];
  const float* Wp = (const float*)d_in[7];
  const float* bp = (const float*)d_in[8];
  const int* idx = (const int*)d_in[9];
  const int* batch = (const int*)d_in[10];
  const int* inv = (const int*)d_in[11];
  float* out = (float*)d_out;

  char* ws = (char*)d_ws;
  short* XP = (short*)(ws + 0);                            // 16,777,216 B
  short* WCAT = (short*)(ws + 16777216);                   //    393,216 B
  short* WPb = (short*)(ws + 17170432);                    //    131,072 B
  float* BCAT = (float*)(ws + 17301504);                   //      3,072 B
  unsigned short* QKVp = (unsigned short*)(ws + 17304576); // 50,331,648 B
  unsigned short* Yb = (unsigned short*)(ws + 67636224);   // 16,777,216 B
  // total ws use: 84,413,440 B

  pack_kernel<<<4224, 256, 0, stream>>>(x, Wq, Wk, Wv, Wp, bq, bk, bv, idx,
                                        XP, WCAT, WPb, BCAT);
  qkv_gemm<<<dim3(256, 6), 256, 0, stream>>>(XP, WCAT, BCAT, QKVp);
  attn_kernel<<<1024, 256, 0, stream>>>(QKVp, batch, Yb);
  out_gemm<<<dim3(192, 2), 256, 0, stream>>>((const short*)Yb, WPb, bp, inv, out);
}